// Round 16
// baseline (285.999 us; speedup 1.0000x reference)
//
#include <hip/hip_runtime.h>
#include <hip/hip_cooperative_groups.h>
#include <math.h>

namespace cg = cooperative_groups;

// Contour-to-distance-map, round 16: single cooperative mega-kernel.
// R13-R15 deltas leave scan/prod attribution under-determined (both scan
// variants cost the same; op models say 3+2us, measurement says ~21-23).
// All in-kernel mechanism theories (branches R9, memory pipe R11, barriers
// R15) are dead. Remaining suspect: dispatch boundaries (ramp/drain of short
// kernels, cold caches after the 268MB poison fill, normalize's 1.2MB out
// round-trip). Fix: fuse scan -> prod -> normalize into ONE cooperative
// launch (harness-blessed) with grid.sync(); prod stays in registers, out is
// written exactly once. Math bit-identical to R14/R15 -> absmax unchanged.

#define INV_2PI 0.15915494309189535f
#define TWO_PI  6.28318530717958648f
#define PI_F    3.14159265358979323846f
#define HPI_F   1.57079632679489662f
#define KK2     200000.0f             // 2*k
#define CTHR    9e-5f                 // |V| below this -> (1-t) != 0

__device__ __forceinline__ float atan01(float q) {
    // A&S 4.4.49: atan(q), q in [0,1], |err| <= 1e-5
    const float z = q * q;
    float p = fmaf(z,  0.0208351f, -0.0851330f);
    p = fmaf(z, p,  0.1801410f);
    p = fmaf(z, p, -0.3302995f);
    p = fmaf(z, p,  0.9998660f);
    return q * p;
}

// (1-t)*copysign(an, -V) for edge (a->b), pixel (px,py), V = line-form cross
__device__ __forceinline__ float corr_term(float ax_, float ay_, float bx_,
                                           float by_, float px, float py,
                                           float V) {
    const float dxc = ax_ - px, dyc = ay_ - py;
    const float dxn = bx_ - px, dyn = by_ - py;
    const float dot = fmaf(dxc, dxn, dyc * dyn);
    const float ay = fabsf(V), ax = fabsf(dot);
    const float mn = fminf(ax, ay), mx = fmaxf(ax, ay);
    const float q  = mn * __builtin_amdgcn_rcpf(fmaxf(mx, 1e-30f));
    float an = atan01(q);
    an = (ay > ax)    ? (HPI_F - an) : an;
    an = (dot < 0.0f) ? (PI_F - an)  : an;
    const float e = __expf(ay * -KK2);
    const float t = (1.0f - e) * __builtin_amdgcn_rcpf(1.0f + e);
    return (1.0f - t) * copysignf(an, -V);
}

__global__ void __launch_bounds__(256, 3)
mega_kernel(const float2* __restrict__ c, int N, int S, float invS,
            float* __restrict__ out, float* __restrict__ wbuf,
            float* __restrict__ bmax) {
    __shared__ union {
        struct { int D[448]; float WC[384]; int lst[16]; int lcnt; } a;
        struct { float2 sv[256]; float cd[4]; int scnt; } b;
    } u;
    __shared__ float s_red[4];

    const int tid  = threadIdx.x;
    const int lane = tid & 63;
    const int wid  = tid >> 6;
    const int bid  = blockIdx.x;
    const float Sf = (float)S;
    cg::grid_group grid = cg::this_grid();

    // ================= Phase A: column scan (blocks 0..S-1) =================
    if (bid < S) {
        const int col = bid;
        const float px = (float)col * invS;

        for (int t = tid; t < 448; t += 256) u.a.D[t] = 0;
        for (int t = tid; t < 384; t += 256) u.a.WC[t] = 0.0f;
        if (tid == 0) u.a.lcnt = 0;
        __syncthreads();

        for (int n = tid; n < N; n += 256) {
            const float2 a = c[n];
            const float2 b = c[(n + 1 < N) ? (n + 1) : 0];
            const float EX = b.x - a.x;
            const float EY = b.y - a.y;
            const float Cc = a.x * b.y - a.y * b.x;
            const float W  = fmaf(-px, EY, Cc);      // V(py) = EX*py + W

            // winding events: +s on j in [ylo,yhi) where s*V(py_j) > 0
            const float ylo = fminf(a.y, b.y);
            const float yhi = fmaxf(a.y, b.y);
            const int s = (b.y > a.y) ? 1 : -1;
            int ja = (int)ceilf(ylo * Sf);
            int jb = (int)ceilf(yhi * Sf);
            ja = max(ja, 0); jb = min(jb, S);
            if (ja < jb) {
                const float Ga = (float)s * fmaf(EX, (float)ja * invS, W);
                const float Gb = (float)s * fmaf(EX, (float)(jb - 1) * invS, W);
                int j0 = ja, j1 = jb;
                if (Ga > 0.0f && Gb > 0.0f) {
                } else if (!(Ga > 0.0f) && !(Gb > 0.0f)) {
                    j1 = j0;
                } else {
                    const float r = -W / EX;
                    const float rj = fminf(fmaxf(r * Sf, -1.0f), 386.0f);
                    int jm = (int)ceilf(rj);
                    jm = min(max(jm, ja), jb);
                    if (Ga > 0.0f) j1 = jm; else j0 = jm;
                }
                if (j0 < j1) {
                    atomicAdd(&u.a.D[j0],  s);
                    atomicAdd(&u.a.D[j1], -s);
                }
            }

            // correction band: j with |V(py_j)| < CTHR
            const float aEX = fabsf(EX);
            if (aEX < 1e-12f) {
                if (fabsf(W) < CTHR) {
                    const int k = atomicAdd(&u.a.lcnt, 1);
                    if (k < 16) u.a.lst[k] = n;
                }
            } else {
                const float r  = -W / EX;
                const float dl = CTHR / aEX;
                float flo = (r - dl) * Sf;
                float fhi = (r + dl) * Sf;
                if (fhi >= 0.0f && flo <= Sf - 1.0f) {
                    flo = fmaxf(flo, 0.0f);
                    fhi = fminf(fhi, Sf - 1.0f);
                    const int jl = (int)ceilf(flo);
                    const int jh = (int)floorf(fhi);
                    if (jh - jl > 24) {
                        const int k = atomicAdd(&u.a.lcnt, 1);
                        if (k < 16) u.a.lst[k] = n;
                    } else {
                        for (int j = jl; j <= jh; ++j) {
                            const float py = (float)j * invS;
                            const float V = fmaf(EX, py, W);
                            if (fabsf(V) < CTHR)
                                atomicAdd(&u.a.WC[j],
                                          corr_term(a.x, a.y, b.x, b.y,
                                                    px, py, V));
                        }
                    }
                }
            }
        }
        __syncthreads();

        // cooperative corrections for wide-band edges (rare)
        const int L = min(u.a.lcnt, 16);
        for (int k = 0; k < L; ++k) {
            const int n = u.a.lst[k];
            const float2 a = c[n];
            const float2 b = c[(n + 1 < N) ? (n + 1) : 0];
            const float EX = b.x - a.x;
            const float EY = b.y - a.y;
            const float W  = fmaf(-px, EY, a.x * b.y - a.y * b.x);
            for (int j = tid; j < S; j += 256) {
                const float py = (float)j * invS;
                const float V = fmaf(EX, py, W);
                if (fabsf(V) < CTHR)
                    atomicAdd(&u.a.WC[j],
                              corr_term(a.x, a.y, b.x, b.y, px, py, V));
            }
        }
        __syncthreads();

        // in-register prefix (wave 0 only): lane L holds D[6L..6L+5]
        if (wid == 0) {
            const int d0 = u.a.D[6 * lane + 0], d1 = u.a.D[6 * lane + 1];
            const int d2 = u.a.D[6 * lane + 2], d3 = u.a.D[6 * lane + 3];
            const int d4 = u.a.D[6 * lane + 4], d5 = u.a.D[6 * lane + 5];
            const int l0 = d0,      l1 = l0 + d1, l2 = l1 + d2;
            const int l3 = l2 + d3, l4 = l3 + d4, l5 = l4 + d5;
            int inc = l5;
            #pragma unroll
            for (int off = 1; off < 64; off <<= 1) {
                const int y = __shfl_up(inc, off, 64);
                if (lane >= off) inc += y;
            }
            const int excl = inc - l5;
            const int jb6 = 6 * lane;
            float* wrow = wbuf + col * S + jb6;
            wrow[0] = fmaf(-TWO_PI, (float)(excl + l0), -u.a.WC[jb6 + 0]);
            wrow[1] = fmaf(-TWO_PI, (float)(excl + l1), -u.a.WC[jb6 + 1]);
            wrow[2] = fmaf(-TWO_PI, (float)(excl + l2), -u.a.WC[jb6 + 2]);
            wrow[3] = fmaf(-TWO_PI, (float)(excl + l3), -u.a.WC[jb6 + 3]);
            wrow[4] = fmaf(-TWO_PI, (float)(excl + l4), -u.a.WC[jb6 + 4]);
            wrow[5] = fmaf(-TWO_PI, (float)(excl + l5), -u.a.WC[jb6 + 5]);
        }
    }

    __threadfence();
    grid.sync();

    // ============== Phase B: tile-pruned prod (all 576 blocks) ==============
    // 16x16 pixel tile; S/16 tiles per dim (384/16 = 24)
    const int nbx = S >> 4;
    const int bi = bid / nbx;
    const int bj = bid - bi * nbx;
    const int i = (bi << 4) + (tid >> 4);
    const int j = (bj << 4) + (tid & 15);
    const float px = (float)i * invS, py = (float)j * invS;
    const float cx = ((float)(bi << 4) + 7.5f) * invS;
    const float cy = ((float)(bj << 4) + 7.5f) * invS;

    float cmin = 1e30f;
    for (int n = tid; n < N; n += 256) {
        const float2 v = c[n];
        const float dx = v.x - cx, dy = v.y - cy;
        cmin = fminf(cmin, fmaf(dx, dx, dy * dy));
    }
    #pragma unroll
    for (int off = 32; off >= 1; off >>= 1)
        cmin = fminf(cmin, __shfl_down(cmin, off, 64));
    if (lane == 0) u.b.cd[wid] = cmin;
    if (tid == 0) u.b.scnt = 0;
    __syncthreads();
    const float minc = fminf(fminf(u.b.cd[0], u.b.cd[1]),
                             fminf(u.b.cd[2], u.b.cd[3]));

    // dist(center,v) <= sqrt(minc) + 2r, 2r = 0.0560 > exact 0.05524
    const float T  = sqrtf(minc) + 0.0560f;
    const float T2 = T * T;

    for (int n = tid; n < N; n += 256) {
        const float2 v = c[n];
        const float dx = v.x - cx, dy = v.y - cy;
        if (fmaf(dx, dx, dy * dy) <= T2) {
            const int k = atomicAdd(&u.b.scnt, 1);
            u.b.sv[k] = v;
        }
    }
    __syncthreads();

    const int M = u.b.scnt;
    float minn = 1e30f;
    for (int k = 0; k < M; ++k) {
        const float2 v = u.b.sv[k];
        const float dx = v.x - px, dy = v.y - py;
        minn = fminf(minn, fmaf(dx, dx, dy * dy));
    }

    const int p = i * S + j;
    const float prod = (wbuf[p] * INV_2PI) * __builtin_amdgcn_sqrtf(minn);

    float v = prod;
    #pragma unroll
    for (int off = 32; off >= 1; off >>= 1)
        v = fmaxf(v, __shfl_down(v, off, 64));
    if (lane == 0) s_red[wid] = v;
    __syncthreads();
    if (tid == 0)
        bmax[bid] = fmaxf(fmaxf(s_red[0], s_red[1]),
                          fmaxf(s_red[2], s_red[3]));

    __threadfence();
    grid.sync();

    // ============ Phase C: global max + normalize (out written once) ========
    const int nb = (int)gridDim.x;
    float m = -INFINITY;
    for (int t = tid; t < nb; t += 256) m = fmaxf(m, bmax[t]);
    #pragma unroll
    for (int off = 32; off >= 1; off >>= 1)
        m = fmaxf(m, __shfl_down(m, off, 64));
    __syncthreads();                       // s_red reuse safety
    if (lane == 0) s_red[wid] = m;
    __syncthreads();
    m = fmaxf(fmaxf(s_red[0], s_red[1]), fmaxf(s_red[2], s_red[3]));
    const float inv = 1.0f / m;

    out[p] = prod * inv;
}

extern "C" void kernel_launch(void* const* d_in, const int* in_sizes, int n_in,
                              void* d_out, int out_size, void* d_ws, size_t ws_size,
                              hipStream_t stream) {
    const float2* contour = (const float2*)d_in[0];
    int N = in_sizes[0] / 2;                             // 200 (<=256)
    int S = (int)(sqrt((double)out_size) + 0.5);         // 384 (= 6*64)
    float invS = 1.0f / (float)S;
    float* out  = (float*)d_out;
    float* bmax = (float*)d_ws;                          // 576 floats
    float* wbuf = (float*)((char*)d_ws + 16384);         // S*S winding grid

    const int total   = S * S;
    int wblocks = total / 256;                           // 576 (exact)

    void* kargs[] = { (void*)&contour, (void*)&N, (void*)&S, (void*)&invS,
                      (void*)&out, (void*)&wbuf, (void*)&bmax };
    hipLaunchCooperativeKernel((const void*)mega_kernel,
                               dim3(wblocks), dim3(256), kargs, 0, stream);
}

// Round 17
// 67.887 us; speedup vs baseline: 4.2129x; 4.2129x over previous
//
#include <hip/hip_runtime.h>
#include <math.h>

// Contour-to-distance-map, round 17.
// R16's mega-kernel (231us, VALUBusy 0.78%) proved grid.sync costs ~100us
// BUT gave the decisive counter: scan+prod+normalize actual VALU work < 2us.
// R13/R14's ~22us "controllable" time is per-dispatch fixed cost (~6-8us x
// 3 short kernels), not compute. Fix: 3 dispatches -> 2. The tile kernel
// computes its own winding: per (tile-column, edge) the R13 event interval
// [j0,j1) is computed bit-identically, clipped to the tile's 16 rows into a
// 16x17 LDS difference array; 16-entry prefix = wind per pixel. Correction
// band clipped to tile rows (float-clamp before int-cast kills the aEX->0
// overflow; wide-band fallback = the natural <=16-row loop). Deletes the
// scan kernel AND the wbuf global round-trip. Math bit-identical per
// (col,row) -> absmax must stay exactly 7.8e-3 (tracer).

#define INV_2PI 0.15915494309189535f
#define TWO_PI  6.28318530717958648f
#define PI_F    3.14159265358979323846f
#define HPI_F   1.57079632679489662f
#define KK2     200000.0f             // 2*k
#define CTHR    9e-5f                 // |V| below this -> (1-t) != 0

__device__ __forceinline__ float atan01(float q) {
    // A&S 4.4.49: atan(q), q in [0,1], |err| <= 1e-5
    const float z = q * q;
    float p = fmaf(z,  0.0208351f, -0.0851330f);
    p = fmaf(z, p,  0.1801410f);
    p = fmaf(z, p, -0.3302995f);
    p = fmaf(z, p,  0.9998660f);
    return q * p;
}

// (1-t)*copysign(an, -V) for edge (a->b), pixel (px,py), V = line-form cross
__device__ __forceinline__ float corr_term(float ax_, float ay_, float bx_,
                                           float by_, float px, float py,
                                           float V) {
    const float dxc = ax_ - px, dyc = ay_ - py;
    const float dxn = bx_ - px, dyn = by_ - py;
    const float dot = fmaf(dxc, dxn, dyc * dyn);
    const float ay = fabsf(V), ax = fabsf(dot);
    const float mn = fminf(ax, ay), mx = fmaxf(ax, ay);
    const float q  = mn * __builtin_amdgcn_rcpf(fmaxf(mx, 1e-30f));
    float an = atan01(q);
    an = (ay > ax)    ? (HPI_F - an) : an;
    an = (dot < 0.0f) ? (PI_F - an)  : an;
    const float e = __expf(ay * -KK2);
    const float t = (1.0f - e) * __builtin_amdgcn_rcpf(1.0f + e);
    return (1.0f - t) * copysignf(an, -V);
}

__global__ void __launch_bounds__(256, 4)
tile_kernel(const float2* __restrict__ c, int N, int S, float invS,
            float* __restrict__ out, float* __restrict__ bmax) {
    __shared__ float2 sc[256];        // contour (N <= 256)
    __shared__ int    D[16][17];      // per-local-column row diff array
    __shared__ float  WC[16][16];     // per-pixel correction
    __shared__ float2 sv[256];        // min-dist candidates
    __shared__ int    scnt;
    __shared__ float  s_cd[4];
    __shared__ float  s_red[4];

    const int tid  = threadIdx.x;
    const int lane = tid & 63;
    const int wid  = tid >> 6;
    const float Sf = (float)S;

    // tile (bi,bj): columns i0..i0+15, rows jt..jt+15
    const int nbx = S >> 4;                       // 24
    const int bi = blockIdx.x / nbx;
    const int bj = blockIdx.x - bi * nbx;
    const int i0 = bi << 4;
    const int jt = bj << 4;

    if (tid < N) sc[tid] = c[tid];
    for (int t = tid; t < 272; t += 256) ((int*)D)[t] = 0;
    WC[tid >> 4][tid & 15] = 0.0f;
    if (tid == 0) scnt = 0;
    __syncthreads();

    // ---- events + corrections: tasks = (local column ci, edge n) ----
    {
        const int ci = tid & 15;
        const float px = (float)(i0 + ci) * invS;
        for (int n = tid >> 4; n < N; n += 16) {
            const float2 a = sc[n];
            const float2 b = sc[(n + 1 < N) ? (n + 1) : 0];
            const float EX = b.x - a.x;
            const float EY = b.y - a.y;
            const float Cc = a.x * b.y - a.y * b.x;
            const float W  = fmaf(-px, EY, Cc);   // V(py) = EX*py + W

            // winding events (bit-identical to R13 scan_kernel)
            const float ylo = fminf(a.y, b.y);
            const float yhi = fmaxf(a.y, b.y);
            const int s = (b.y > a.y) ? 1 : -1;
            int ja = (int)ceilf(ylo * Sf);
            int jb = (int)ceilf(yhi * Sf);
            ja = max(ja, 0); jb = min(jb, S);
            if (ja < jb) {
                const float Ga = (float)s * fmaf(EX, (float)ja * invS, W);
                const float Gb = (float)s * fmaf(EX, (float)(jb - 1) * invS, W);
                int j0 = ja, j1 = jb;
                if (Ga > 0.0f && Gb > 0.0f) {
                } else if (!(Ga > 0.0f) && !(Gb > 0.0f)) {
                    j1 = j0;
                } else {
                    const float r = -W / EX;      // EX != 0 (signs differ)
                    const float rj = fminf(fmaxf(r * Sf, -1.0f), 386.0f);
                    int jm = (int)ceilf(rj);
                    jm = min(max(jm, ja), jb);
                    if (Ga > 0.0f) j1 = jm; else j0 = jm;
                }
                const int j0c = max(j0, jt);
                const int j1c = min(j1, jt + 16);
                if (j0c < j1c) {
                    atomicAdd(&D[ci][j0c - jt],  s);
                    atomicAdd(&D[ci][j1c - jt], -s);
                }
            }

            // correction band clipped to tile rows (float-clamp, no overflow)
            const float aEX = fabsf(EX);
            float flo, fhi;
            if (aEX < 1e-12f) {
                if (fabsf(W) < CTHR) { flo = (float)jt; fhi = (float)(jt + 15); }
                else                 { flo = 1.0f;      fhi = 0.0f; }
            } else {
                const float r  = -W / EX;
                const float dl = CTHR / aEX;
                flo = (r - dl) * Sf;
                fhi = (r + dl) * Sf;
            }
            flo = fmaxf(flo, (float)jt);
            fhi = fminf(fhi, (float)(jt + 15));
            if (flo <= fhi) {
                const int jl = (int)ceilf(flo);
                const int jh = (int)floorf(fhi);
                for (int j = jl; j <= jh; ++j) {
                    const float py = (float)j * invS;
                    const float V = fmaf(EX, py, W);
                    if (fabsf(V) < CTHR)
                        atomicAdd(&WC[ci][j - jt],
                                  corr_term(a.x, a.y, b.x, b.y, px, py, V));
                }
            }
        }
    }

    // ---- min-dist candidate pass 1 (runs on same barrier interval) ----
    const int i = i0 + (tid >> 4);
    const int j = jt + (tid & 15);
    const float px = (float)i * invS, py = (float)j * invS;
    const float cx = ((float)i0 + 7.5f) * invS;
    const float cy = ((float)jt + 7.5f) * invS;

    float cmin = 1e30f;
    if (tid < N) {
        const float2 v = sc[tid];
        const float dx = v.x - cx, dy = v.y - cy;
        cmin = fmaf(dx, dx, dy * dy);
    }
    #pragma unroll
    for (int off = 32; off >= 1; off >>= 1)
        cmin = fminf(cmin, __shfl_down(cmin, off, 64));
    if (lane == 0) s_cd[wid] = cmin;
    __syncthreads();

    const float minc = fminf(fminf(s_cd[0], s_cd[1]), fminf(s_cd[2], s_cd[3]));
    // dist(center,v) <= sqrt(minc) + 2r, 2r = 0.0560 > exact 0.05524
    const float T  = sqrtf(minc) + 0.0560f;
    const float T2 = T * T;

    if (tid < N) {
        const float2 v = sc[tid];
        const float dx = v.x - cx, dy = v.y - cy;
        if (fmaf(dx, dx, dy * dy) <= T2) {
            const int k = atomicAdd(&scnt, 1);
            sv[k] = v;
        }
    }
    __syncthreads();

    // ---- per-pixel wind (16-entry prefix), min-dist, prod ----
    const int cl = tid >> 4;          // pixel's local column
    const int rl = tid & 15;          // pixel's local row
    int wind = 0;
    #pragma unroll
    for (int q = 0; q < 16; ++q)
        wind += (q <= rl) ? D[cl][q] : 0;
    const float w = fmaf(-TWO_PI, (float)wind, -WC[cl][rl]);

    const int M = scnt;
    float minn = 1e30f;
    for (int k = 0; k < M; ++k) {
        const float2 v = sv[k];
        const float dx = v.x - px, dy = v.y - py;
        minn = fminf(minn, fmaf(dx, dx, dy * dy));
    }

    const int p = i * S + j;
    const float prod = (w * INV_2PI) * __builtin_amdgcn_sqrtf(minn);
    out[p] = prod;

    float v = prod;
    #pragma unroll
    for (int off = 32; off >= 1; off >>= 1)
        v = fmaxf(v, __shfl_down(v, off, 64));
    if (lane == 0) s_red[wid] = v;
    __syncthreads();
    if (tid == 0)
        bmax[blockIdx.x] = fmaxf(fmaxf(s_red[0], s_red[1]),
                                 fmaxf(s_red[2], s_red[3]));
}

__global__ void __launch_bounds__(256)
normalize_kernel(float4* __restrict__ out4, const float* __restrict__ bmax,
                 int nmax, int total4) {
    const int tid  = threadIdx.x;
    const int lane = tid & 63;
    const int wid  = tid >> 6;

    float m = -INFINITY;
    for (int t = tid; t < nmax; t += 256) m = fmaxf(m, bmax[t]);
    #pragma unroll
    for (int off = 32; off >= 1; off >>= 1)
        m = fmaxf(m, __shfl_down(m, off, 64));
    __shared__ float sm[4];
    if (lane == 0) sm[wid] = m;
    __syncthreads();
    m = fmaxf(fmaxf(sm[0], sm[1]), fmaxf(sm[2], sm[3]));
    const float inv = 1.0f / m;

    const int idx = blockIdx.x * 256 + tid;
    if (idx < total4) {
        float4 v = out4[idx];
        v.x *= inv; v.y *= inv; v.z *= inv; v.w *= inv;
        out4[idx] = v;
    }
}

extern "C" void kernel_launch(void* const* d_in, const int* in_sizes, int n_in,
                              void* d_out, int out_size, void* d_ws, size_t ws_size,
                              hipStream_t stream) {
    const float2* contour = (const float2*)d_in[0];
    const int N = in_sizes[0] / 2;                       // 200 (<=256)
    const int S = (int)(sqrt((double)out_size) + 0.5);   // 384
    const float invS = 1.0f / (float)S;
    float* out  = (float*)d_out;
    float* bmax = (float*)d_ws;                          // 576 floats

    const int total   = S * S;
    const int tblocks = total / 256;                     // 576 (exact)
    tile_kernel<<<tblocks, 256, 0, stream>>>(contour, N, S, invS, out, bmax);

    const int total4  = total / 4;
    const int nblocks = (total4 + 255) / 256;            // 144
    normalize_kernel<<<nblocks, 256, 0, stream>>>((float4*)out, bmax,
                                                  tblocks, total4);
}

// Round 18
// 64.083 us; speedup vs baseline: 4.4629x; 1.0594x over previous
//
#include <hip/hip_runtime.h>
#include <math.h>

// Contour-to-distance-map, FINAL (revert to R14 = best measured, 64.3us).
// Session model (18 rounds): total = 40us ws-poison fill (268MB @85% HBM
// peak, harness-fixed) + ~24us harness reset chain (dozens of tiny
// hipMemsetAsync/restore dispatches, concurrent with our stream) + our
// kernels (~2us true VALU work, R16 VALUBusy evidence). R14-R17 structural
// variants all landed 64-68 independent of kernel content -> R14 sits on
// the harness floor. Algorithm: O(S*N) scanline winding (difference-array
// events + prefix sum, exact tanh-weight correction only in the |V|<9e-5
// band where fp32 (1-t)!=0) + tile-pruned min-distance (triangle-inequality
// candidate set, bit-exact superset) + max-normalize.

#define INV_2PI 0.15915494309189535f
#define TWO_PI  6.28318530717958648f
#define PI_F    3.14159265358979323846f
#define HPI_F   1.57079632679489662f
#define KK2     200000.0f             // 2*k
#define CTHR    9e-5f                 // |V| below this -> (1-t) != 0

__device__ __forceinline__ float atan01(float q) {
    // A&S 4.4.49: atan(q), q in [0,1], |err| <= 1e-5
    const float z = q * q;
    float p = fmaf(z,  0.0208351f, -0.0851330f);
    p = fmaf(z, p,  0.1801410f);
    p = fmaf(z, p, -0.3302995f);
    p = fmaf(z, p,  0.9998660f);
    return q * p;
}

// (1-t)*copysign(an, -V) for edge (a->b), pixel (px,py), V = line-form cross
__device__ __forceinline__ float corr_term(float ax_, float ay_, float bx_,
                                           float by_, float px, float py,
                                           float V) {
    const float dxc = ax_ - px, dyc = ay_ - py;
    const float dxn = bx_ - px, dyn = by_ - py;
    const float dot = fmaf(dxc, dxn, dyc * dyn);
    const float ay = fabsf(V), ax = fabsf(dot);
    const float mn = fminf(ax, ay), mx = fmaxf(ax, ay);
    const float q  = mn * __builtin_amdgcn_rcpf(fmaxf(mx, 1e-30f));
    float an = atan01(q);
    an = (ay > ax)    ? (HPI_F - an) : an;
    an = (dot < 0.0f) ? (PI_F - an)  : an;
    const float e = __expf(ay * -KK2);
    const float t = (1.0f - e) * __builtin_amdgcn_rcpf(1.0f + e);
    return (1.0f - t) * copysignf(an, -V);
}

__global__ void __launch_bounds__(256)
scan_kernel(const float2* __restrict__ c, int N, int S, float invS,
            float* __restrict__ wbuf) {
    __shared__ int   D[512];          // difference array (slots >=S harmless)
    __shared__ float WC[512];         // correction accumulator
    __shared__ int   lst[16];
    __shared__ int   lcnt;

    const int tid = threadIdx.x;
    const int col = blockIdx.x;       // column i (x index)
    const float px = (float)col * invS;
    const float Sf = (float)S;

    for (int t = tid; t < 512; t += 256) { D[t] = 0; WC[t] = 0.0f; }
    if (tid == 0) lcnt = 0;
    __syncthreads();

    for (int n = tid; n < N; n += 256) {
        const float2 a = c[n];
        const float2 b = c[(n + 1 < N) ? (n + 1) : 0];
        const float EX = b.x - a.x;
        const float EY = b.y - a.y;
        const float Cc = a.x * b.y - a.y * b.x;
        const float W  = fmaf(-px, EY, Cc);      // V(py) = EX*py + W

        // ---- winding events: +s on j in [ylo,yhi) where s*V(py_j) > 0 ----
        const float ylo = fminf(a.y, b.y);
        const float yhi = fmaxf(a.y, b.y);
        const int s = (b.y > a.y) ? 1 : -1;
        int ja = (int)ceilf(ylo * Sf);           // py >= ylo  (half-open hi)
        int jb = (int)ceilf(yhi * Sf);
        ja = max(ja, 0); jb = min(jb, S);
        if (ja < jb) {
            const float Ga = (float)s * fmaf(EX, (float)ja * invS, W);
            const float Gb = (float)s * fmaf(EX, (float)(jb - 1) * invS, W);
            int j0 = ja, j1 = jb;
            if (Ga > 0.0f && Gb > 0.0f) {
                // full range
            } else if (!(Ga > 0.0f) && !(Gb > 0.0f)) {
                j1 = j0;                         // empty
            } else {
                const float r = -W / EX;         // EX != 0 (signs differ)
                const float rj = fminf(fmaxf(r * Sf, -1.0f), 386.0f);
                int jm = (int)ceilf(rj);
                jm = min(max(jm, ja), jb);
                if (Ga > 0.0f) j1 = jm; else j0 = jm;
            }
            if (j0 < j1) {
                atomicAdd(&D[j0],  s);
                atomicAdd(&D[j1], -s);
            }
        }

        // ---- correction band: j with |V(py_j)| < CTHR ----
        const float aEX = fabsf(EX);
        if (aEX < 1e-12f) {
            if (fabsf(W) < CTHR) {
                const int k = atomicAdd(&lcnt, 1);
                if (k < 16) lst[k] = n;
            }
        } else {
            const float r  = -W / EX;
            const float dl = CTHR / aEX;
            float flo = (r - dl) * Sf;
            float fhi = (r + dl) * Sf;
            if (fhi >= 0.0f && flo <= Sf - 1.0f) {
                flo = fmaxf(flo, 0.0f);
                fhi = fminf(fhi, Sf - 1.0f);
                const int jl = (int)ceilf(flo);
                const int jh = (int)floorf(fhi);
                if (jh - jl > 12) {
                    const int k = atomicAdd(&lcnt, 1);
                    if (k < 16) lst[k] = n;
                } else {
                    for (int j = jl; j <= jh; ++j) {
                        const float py = (float)j * invS;
                        const float V = fmaf(EX, py, W);
                        if (fabsf(V) < CTHR)
                            atomicAdd(&WC[j],
                                      corr_term(a.x, a.y, b.x, b.y, px, py, V));
                    }
                }
            }
        }
    }
    __syncthreads();

    // ---- cooperative corrections for wide-band edges (rare) ----
    const int L = min(lcnt, 16);
    for (int k = 0; k < L; ++k) {
        const int n = lst[k];
        const float2 a = c[n];
        const float2 b = c[(n + 1 < N) ? (n + 1) : 0];
        const float EX = b.x - a.x;
        const float EY = b.y - a.y;
        const float W  = fmaf(-px, EY, a.x * b.y - a.y * b.x);
        for (int j = tid; j < S; j += 256) {
            const float py = (float)j * invS;
            const float V = fmaf(EX, py, W);
            if (fabsf(V) < CTHR)
                atomicAdd(&WC[j], corr_term(a.x, a.y, b.x, b.y, px, py, V));
        }
    }
    __syncthreads();

    // ---- inclusive prefix sum of D over 512 slots (Hillis-Steele) ----
    #pragma unroll
    for (int off = 1; off < 512; off <<= 1) {
        const int j0 = tid, j1 = tid + 256;
        const int v0 = D[j0] + ((j0 >= off) ? D[j0 - off] : 0);
        const int v1 = D[j1] + ((j1 >= off) ? D[j1 - off] : 0);
        __syncthreads();
        D[j0] = v0; D[j1] = v1;
        __syncthreads();
    }

    // ---- w(j) = -2*pi*wind(j) - WC(j) ----
    for (int j = tid; j < S; j += 256)
        wbuf[col * S + j] = fmaf(-TWO_PI, (float)D[j], -WC[j]);
}

__global__ void __launch_bounds__(256)
prod_kernel(const float2* __restrict__ c, int N, int S, float invS,
            const float* __restrict__ wbuf, float* __restrict__ out,
            float* __restrict__ bmax) {
    __shared__ float2 sv[256];        // candidate vertices (cap N<=256)
    __shared__ int    scnt;
    __shared__ float  s_cd[4];
    __shared__ float  s_red[4];

    const int tid  = threadIdx.x;
    const int lane = tid & 63;
    const int wid  = tid >> 6;

    // 16x16 pixel tile; S/16 tiles per dim (384/16 = 24)
    const int nbx = S >> 4;
    const int bi = blockIdx.x / nbx;
    const int bj = blockIdx.x - bi * nbx;
    const int i = (bi << 4) + (tid >> 4);
    const int j = (bj << 4) + (tid & 15);
    const float px = (float)i * invS, py = (float)j * invS;

    // tile center
    const float cx = ((float)(bi << 4) + 7.5f) * invS;
    const float cy = ((float)(bj << 4) + 7.5f) * invS;

    // pass 1: min center-distance^2 over all vertices
    float cmin = 1e30f;
    for (int n = tid; n < N; n += 256) {
        const float2 v = c[n];
        const float dx = v.x - cx, dy = v.y - cy;
        cmin = fminf(cmin, fmaf(dx, dx, dy * dy));
    }
    #pragma unroll
    for (int off = 32; off >= 1; off >>= 1)
        cmin = fminf(cmin, __shfl_down(cmin, off, 64));
    if (lane == 0) s_cd[wid] = cmin;
    if (tid == 0) scnt = 0;
    __syncthreads();
    const float minc = fminf(fminf(s_cd[0], s_cd[1]), fminf(s_cd[2], s_cd[3]));

    // candidate threshold: dist(center,v) <= sqrt(minc) + 2r, 2r=0.0560
    // (exact 2r = 2*sqrt(2)*7.5/384 = 0.05524; inflated for fp safety)
    const float T  = sqrtf(minc) + 0.0560f;
    const float T2 = T * T;

    // pass 2: append candidates
    for (int n = tid; n < N; n += 256) {
        const float2 v = c[n];
        const float dx = v.x - cx, dy = v.y - cy;
        if (fmaf(dx, dx, dy * dy) <= T2) {
            const int k = atomicAdd(&scnt, 1);
            sv[k] = v;
        }
    }
    __syncthreads();

    // per-pixel min over candidates (LDS broadcast reads; superset of the
    // argmin with bit-identical fmaf -> minn exact)
    const int M = scnt;
    float minn = 1e30f;
    for (int k = 0; k < M; ++k) {
        const float2 v = sv[k];
        const float dx = v.x - px, dy = v.y - py;
        minn = fminf(minn, fmaf(dx, dx, dy * dy));
    }

    const int p = i * S + j;
    const float prod = (wbuf[p] * INV_2PI) * __builtin_amdgcn_sqrtf(minn);
    out[p] = prod;

    float v = prod;
    #pragma unroll
    for (int off = 32; off >= 1; off >>= 1)
        v = fmaxf(v, __shfl_down(v, off, 64));
    if (lane == 0) s_red[wid] = v;
    __syncthreads();
    if (tid == 0)
        bmax[blockIdx.x] = fmaxf(fmaxf(s_red[0], s_red[1]),
                                 fmaxf(s_red[2], s_red[3]));
}

__global__ void __launch_bounds__(256)
normalize_kernel(float4* __restrict__ out4, const float* __restrict__ bmax,
                 int nmax, int total4) {
    const int tid  = threadIdx.x;
    const int lane = tid & 63;
    const int wid  = tid >> 6;

    float m = -INFINITY;
    for (int t = tid; t < nmax; t += 256) m = fmaxf(m, bmax[t]);
    #pragma unroll
    for (int off = 32; off >= 1; off >>= 1)
        m = fmaxf(m, __shfl_down(m, off, 64));
    __shared__ float sm[4];
    if (lane == 0) sm[wid] = m;
    __syncthreads();
    m = fmaxf(fmaxf(sm[0], sm[1]), fmaxf(sm[2], sm[3]));
    const float inv = 1.0f / m;

    const int idx = blockIdx.x * 256 + tid;
    if (idx < total4) {
        float4 v = out4[idx];
        v.x *= inv; v.y *= inv; v.z *= inv; v.w *= inv;
        out4[idx] = v;
    }
}

extern "C" void kernel_launch(void* const* d_in, const int* in_sizes, int n_in,
                              void* d_out, int out_size, void* d_ws, size_t ws_size,
                              hipStream_t stream) {
    const float2* contour = (const float2*)d_in[0];
    const int N = in_sizes[0] / 2;                       // 200 (<=256)
    const int S = (int)(sqrt((double)out_size) + 0.5);   // 384
    const float invS = 1.0f / (float)S;
    float* out  = (float*)d_out;
    float* bmax = (float*)d_ws;                          // 576 floats
    float* wbuf = (float*)((char*)d_ws + 16384);         // S*S winding grid

    scan_kernel<<<S, 256, 0, stream>>>(contour, N, S, invS, wbuf);

    const int total  = S * S;
    const int pblocks = total / 256;                     // 576 (exact)
    prod_kernel<<<pblocks, 256, 0, stream>>>(contour, N, S, invS, wbuf,
                                             out, bmax);

    const int total4  = total / 4;
    const int nblocks = (total4 + 255) / 256;            // 144
    normalize_kernel<<<nblocks, 256, 0, stream>>>((float4*)out, bmax,
                                                  pblocks, total4);
}